// Round 7
// baseline (245.124 us; speedup 1.0000x reference)
//
#include <hip/hip_runtime.h>

// ---------------- constants ----------------
#define Bk 32      // batch
#define Nn 128     // nodes
#define Cc 128     // in channels
#define HE 64      // edge hidden
#define BN_EPS 1e-5f

typedef __attribute__((ext_vector_type(8))) short short8;
typedef __attribute__((ext_vector_type(4))) float floatx4;

// workspace offsets (floats)
#define OFF_UV   ((size_t)0)         // 524288  uv f32 [4096][128]
#define OFF_AP   ((size_t)524288)    // 524288  masked exp scores (upper-tri valid)
#define OFF_LB   ((size_t)1048576)   // 524288 f = bf16 L [2 rel][32 b][128][128]
#define OFF_H0   ((size_t)1572864)   // 262144
#define OFF_H1   ((size_t)1835008)   // 1048576
#define OFF_POOL ((size_t)2883584)   // 16384
#define OFF_WC   ((size_t)2899968)   // 5120
#define OFF_BC   ((size_t)2905088)   // 16
#define OFF_XB0  ((size_t)2905104)   // 262144 f = bf16 x
#define OFF_XB   ((size_t)3167248)   // 3145728 f = bf16 Xcat [4096][1536max]
#define OFF_WT   ((size_t)6312976)   // 475136 f (Wt0,Wt1,Wt2,Wuv)
#define OFF_L2M  ((size_t)6788112)   // 524288 f = bf16 L2m=2L^2-I [2 rel][32 b][128][128]
#define WUV_OFS  933888              // ushort offset of Wuv inside WT region

__device__ __forceinline__ unsigned short f2b(float f) {
    unsigned int x = __float_as_uint(f);
    unsigned int r = x + 0x7FFFu + ((x >> 16) & 1u);
    return (unsigned short)(r >> 16);
}

// ---------------- prep: weight transposes (bf16), Wuv, folded classifier, x->bf16 ----------------
__global__ __launch_bounds__(256) void prep_all(const float* __restrict__ W0,
                                                const float* __restrict__ W1,
                                                const float* __restrict__ W2,
                                                const float* __restrict__ eW1,
                                                const float* __restrict__ fW1,
                                                const float* __restrict__ fb1,
                                                const float* __restrict__ fW2,
                                                const float* __restrict__ fb2,
                                                const float* __restrict__ x,
                                                unsigned short* __restrict__ Wt,
                                                float* __restrict__ Wc,
                                                float* __restrict__ bc,
                                                unsigned short* __restrict__ xb0) {
    __shared__ unsigned short Ts[64][65];
    int bid = blockIdx.x, tid = threadIdx.x;
    if (bid < 228) {
        const float* src; unsigned short* dst; int N, ldK, k0, n0;
        if (bid < 12)      { src = W0; dst = Wt;          N = 64;  ldK = 768;  k0 = bid * 64;        n0 = 0; }
        else if (bid < 36) { int t = bid - 12; src = W1; dst = Wt + 49152;  N = 256; ldK = 384;  k0 = (t % 6) * 64;  n0 = (t / 6) * 64; }
        else               { int t = bid - 36; src = W2; dst = Wt + 147456; N = 512; ldK = 1536; k0 = (t % 24) * 64; n0 = (t / 24) * 64; }
#pragma unroll
        for (int p = 0; p < 16; ++p) {
            int e = tid + p * 256; int r = e >> 6, c = e & 63;
            Ts[r][c] = f2b(src[(size_t)(k0 + r) * N + n0 + c]);
        }
        __syncthreads();
#pragma unroll
        for (int p = 0; p < 16; ++p) {
            int e = tid + p * 256; int n = e >> 6, k = e & 63;
            dst[(size_t)(n0 + n) * ldK + k0 + k] = Ts[k][n];
        }
        return;
    }
    if (bid < 232) {
        int tt = bid - 228;
        int half = tt >> 1, kt = tt & 1;
        int k0 = kt * 64;
        unsigned short* Wuv = Wt + WUV_OFS;
#pragma unroll
        for (int p = 0; p < 16; ++p) {
            int e = tid + p * 256; int r = e >> 6, c = e & 63;
            Ts[r][c] = f2b(eW1[(size_t)(half * 128 + k0 + r) * 64 + c]);
        }
        __syncthreads();
#pragma unroll
        for (int p = 0; p < 16; ++p) {
            int e = tid + p * 256; int n = e >> 6, k = e & 63;
            Wuv[(size_t)(half * 64 + n) * 128 + k0 + k] = Ts[k][n];
        }
        return;
    }
    if (bid < 253) {
        int e = (bid - 232) * 256 + tid;
        if (e < 5120) {
            int i = e / 10, j = e - i * 10;
            float acc = 0.f;
            for (int h = 0; h < 256; ++h) acc += fW1[(size_t)i * 256 + h] * fW2[(size_t)h * 10 + j];
            Wc[e] = acc;
        } else if (e < 5130) {
            int j = e - 5120;
            float acc = fb2[j];
            for (int h = 0; h < 256; ++h) acc += fb1[h] * fW2[(size_t)h * 10 + j];
            bc[j] = acc;
        }
        return;
    }
    {
        int idx = (bid - 253) * 256 + tid;
        float4 vv = ((const float4*)x)[idx];
        ushort4 o;
        o.x = f2b(vv.x); o.y = f2b(vv.y); o.z = f2b(vv.z); o.w = f2b(vv.w);
        ((ushort4*)xb0)[idx] = o;
    }
}

// ---------------- uv = x @ Wuv (+eb1 on u cols) via bf16 MFMA ----------------
__global__ __launch_bounds__(256) void uv_mfma(const unsigned short* __restrict__ xb0,
                                               const unsigned short* __restrict__ Wuv,
                                               const float* __restrict__ eb1,
                                               float* __restrict__ uv) {
    __shared__ __align__(16) unsigned short As[128 * 40];
    __shared__ __align__(16) unsigned short Bs[64 * 40];
    int tid = threadIdx.x;
    int w = tid >> 6, lane = tid & 63, quad = lane >> 4, lr = lane & 15;
    int row0 = blockIdx.y * 128, col0 = blockIdx.x * 64;
    floatx4 acc[2][4];
#pragma unroll
    for (int rt = 0; rt < 2; ++rt)
#pragma unroll
        for (int ct = 0; ct < 4; ++ct) acc[rt][ct] = (floatx4){0.f, 0.f, 0.f, 0.f};
    int arow[2], asub[2];
#pragma unroll
    for (int i = 0; i < 2; ++i) { int ch = tid + i * 256; arow[i] = ch >> 2; asub[i] = ch & 3; }
    int brow = tid >> 2, bsub = tid & 3;
    for (int k0 = 0; k0 < 128; k0 += 32) {
        short8 ra[2];
#pragma unroll
        for (int i = 0; i < 2; ++i)
            ra[i] = *(const short8*)(xb0 + (size_t)(row0 + arow[i]) * 128 + k0 + asub[i] * 8);
        short8 rb = *(const short8*)(Wuv + (size_t)(col0 + brow) * 128 + k0 + bsub * 8);
        __syncthreads();
#pragma unroll
        for (int i = 0; i < 2; ++i) *(short8*)&As[arow[i] * 40 + asub[i] * 8] = ra[i];
        *(short8*)&Bs[brow * 40 + bsub * 8] = rb;
        __syncthreads();
        short8 a[2], b[4];
#pragma unroll
        for (int rt = 0; rt < 2; ++rt)
            a[rt] = *(const short8*)&As[(w * 32 + rt * 16 + lr) * 40 + quad * 8];
#pragma unroll
        for (int ct = 0; ct < 4; ++ct)
            b[ct] = *(const short8*)&Bs[(ct * 16 + lr) * 40 + quad * 8];
#pragma unroll
        for (int rt = 0; rt < 2; ++rt)
#pragma unroll
            for (int ct = 0; ct < 4; ++ct)
                acc[rt][ct] = __builtin_amdgcn_mfma_f32_16x16x32_bf16(a[rt], b[ct], acc[rt][ct], 0, 0, 0);
    }
#pragma unroll
    for (int rt = 0; rt < 2; ++rt) {
        int rbase = row0 + w * 32 + rt * 16 + quad * 4;
#pragma unroll
        for (int ct = 0; ct < 4; ++ct) {
            int col = col0 + ct * 16 + lr;
            float bi = (col < 64) ? eb1[col] : 0.f;
#pragma unroll
            for (int reg = 0; reg < 4; ++reg)
                uv[(size_t)(rbase + reg) * 128 + col] = acc[rt][ct][reg] + bi;
        }
    }
}

// ---------------- symmetric masked-exp edge scores (upper-tri tile pairs only) ----------------
__global__ __launch_bounds__(256) void edge_sym(const float* __restrict__ uv,
                                                const float* __restrict__ eW2,
                                                const float* __restrict__ eb2,
                                                const float* __restrict__ mask,
                                                float* __restrict__ ap) {
    __shared__ __align__(16) float ui[16][68], vi[16][68], uj[16][68], vj[16][68];
    __shared__ __align__(16) float w2[64];
    int t = blockIdx.x, b = blockIdx.y;
    int ti = 0, rem = t;
    for (;;) { int w = 8 - ti; if (rem < w) break; rem -= w; ++ti; }
    int tj = ti + rem;
    int i0 = ti * 16, j0 = tj * 16;
    int tid = threadIdx.x;
    int r = tid >> 4, c4 = (tid & 15) * 4;
    const float* uvb = uv + (size_t)b * Nn * 128;
    *(float4*)&ui[r][c4] = *(const float4*)(uvb + (size_t)(i0 + r) * 128 + c4);
    *(float4*)&vi[r][c4] = *(const float4*)(uvb + (size_t)(i0 + r) * 128 + 64 + c4);
    *(float4*)&uj[r][c4] = *(const float4*)(uvb + (size_t)(j0 + r) * 128 + c4);
    *(float4*)&vj[r][c4] = *(const float4*)(uvb + (size_t)(j0 + r) * 128 + 64 + c4);
    if (tid < 64) w2[tid] = eW2[tid];
    __syncthreads();
    int il = tid >> 4, jl = tid & 15;
    int gi = i0 + il, gj = j0 + jl;
    if (gj <= gi) return;
    float d = 0.f;
#pragma unroll
    for (int h4 = 0; h4 < 16; ++h4) {
        float4 a1 = *(const float4*)&ui[il][h4 * 4];
        float4 b1 = *(const float4*)&vj[jl][h4 * 4];
        float4 a2 = *(const float4*)&uj[jl][h4 * 4];
        float4 b2 = *(const float4*)&vi[il][h4 * 4];
        float4 ww = *(const float4*)&w2[h4 * 4];
        d += (fmaxf(a1.x + b1.x, 0.f) + fmaxf(a2.x + b2.x, 0.f)) * ww.x
           + (fmaxf(a1.y + b1.y, 0.f) + fmaxf(a2.y + b2.y, 0.f)) * ww.y
           + (fmaxf(a1.z + b1.z, 0.f) + fmaxf(a2.z + b2.z, 0.f)) * ww.z
           + (fmaxf(a1.w + b1.w, 0.f) + fmaxf(a2.w + b2.w, 0.f)) * ww.w;
    }
    float p = 0.5f * d + eb2[0];
    float mi = mask[b * Nn + gi], mj = mask[b * Nn + gj];
    float val = (mi != 0.f && mj != 0.f) ? expf(fminf(p, 80.f)) : 0.f;
    ap[((size_t)(b * Nn + gi)) * Nn + gj] = val;
}

// ---------------- merged adjacency -> L (bf16) AND L2m = 2L^2 - I (bf16 MFMA) ----------------
// blocks [0,32): An path (rel 1, symmetric L); blocks [32,64): input-A path (rel 0)
__global__ __launch_bounds__(256) void adj_L2(const float* __restrict__ ap,
                                              const float* __restrict__ A,
                                              unsigned short* __restrict__ Lb,
                                              unsigned short* __restrict__ L2m) {
    __shared__ float apS[128][129];
    __shared__ __align__(16) unsigned short LbS[128 * 136];
    __shared__ __align__(16) unsigned short LbT[128 * 136];
    __shared__ float part[256];
    __shared__ float sc1[128], t1S[128], sc2[128];
    int bid = blockIdx.x, tid = threadIdx.x;
    int w = tid >> 6, lane = tid & 63, quad = lane >> 4, lr = lane & 15;
    int rel, b;
    if (bid < 32) {
        rel = 1; b = bid;
        const float* apg = ap + (size_t)b * Nn * Nn;
        for (int k = 0; k < 64; ++k) {
            int idx = tid + k * 256;
            int i = idx >> 7, j = idx & 127;
            float g = apg[idx];
            apS[i][j] = (j > i) ? g : 0.f;
        }
        __syncthreads();
        {
            int row = tid >> 1, half = tid & 1;
            float s0 = 0.f;
            for (int j = half * 64; j < half * 64 + 64; ++j) s0 += apS[row][j];
            part[tid] = s0;
        }
        __syncthreads();
        if (tid < 128) {
            float rsum = part[tid * 2] + part[tid * 2 + 1];
            sc1[tid] = (rsum == 0.f) ? 1.f : (1.f / rsum);
            t1S[tid] = (rsum == 0.f) ? 0.f : 1.f;
        }
        __syncthreads();
        {
            int col = tid >> 1, half = tid & 1;
            float s0 = 0.f;
            for (int j = half * 64; j < half * 64 + 64; ++j) s0 += apS[j][col] * sc1[j];
            part[tid] = s0;
        }
        __syncthreads();
        if (tid < 128) sc2[tid] = rsqrtf(t1S[tid] + part[tid * 2] + part[tid * 2 + 1] + 1e-5f);
        __syncthreads();
        unsigned short* Lo = Lb + ((size_t)(Bk + b)) * Nn * Nn;
        for (int k = 0; k < 64; ++k) {
            int idx = tid + k * 256;
            int i = idx >> 7, j = idx & 127;
            float an = apS[i][j] * sc1[i] + apS[j][i] * sc1[j];
            unsigned short hv = f2b(sc2[i] * an * sc2[j]);
            LbS[i * 136 + j] = hv;          // symmetric: rows == cols
            Lo[idx] = hv;
        }
    } else {
        rel = 0; b = bid - 32;
        const float* Ar = A + (size_t)b * Nn * Nn;
        {
            int j = tid & 127, half = tid >> 7;
            float sum = 0.f;
            for (int i = half * 64; i < half * 64 + 64; ++i) sum += Ar[i * Nn + j];
            part[tid] = sum;
        }
        __syncthreads();
        if (tid < 128) sc2[tid] = rsqrtf(part[tid] + part[tid + 128] + 1e-5f);
        __syncthreads();
        unsigned short* Lo = Lb + (size_t)b * Nn * Nn;
        for (int k = 0; k < 64; ++k) {
            int idx = tid + k * 256;
            int i = idx >> 7, j = idx & 127;
            unsigned short hv = f2b(sc2[i] * Ar[idx] * sc2[j]);
            LbS[i * 136 + j] = hv;
            LbT[j * 136 + i] = hv;          // explicit transpose (A not symmetric)
            Lo[idx] = hv;
        }
    }
    __syncthreads();
    // ---- L2m = 2*L@L - I via MFMA; B-frags from LbS (symmetric) or LbT ----
    const unsigned short* Bsrc = (bid < 32) ? LbS : LbT;
    floatx4 acc[2][8];
#pragma unroll
    for (int rt = 0; rt < 2; ++rt)
#pragma unroll
        for (int ct = 0; ct < 8; ++ct) acc[rt][ct] = (floatx4){0.f, 0.f, 0.f, 0.f};
#pragma unroll
    for (int kc = 0; kc < 4; ++kc) {
        short8 a[2], bb[8];
#pragma unroll
        for (int rt = 0; rt < 2; ++rt)
            a[rt] = *(const short8*)&LbS[((w * 2 + rt) * 16 + lr) * 136 + kc * 32 + quad * 8];
#pragma unroll
        for (int ct = 0; ct < 8; ++ct)
            bb[ct] = *(const short8*)&Bsrc[(ct * 16 + lr) * 136 + kc * 32 + quad * 8];
#pragma unroll
        for (int rt = 0; rt < 2; ++rt)
#pragma unroll
            for (int ct = 0; ct < 8; ++ct)
                acc[rt][ct] = __builtin_amdgcn_mfma_f32_16x16x32_bf16(a[rt], bb[ct], acc[rt][ct], 0, 0, 0);
    }
    // stage bf16 L2m into apS region, then coalesced copy out
    unsigned short* stage = (unsigned short*)&apS[0][0];
#pragma unroll
    for (int rt = 0; rt < 2; ++rt) {
        int rb = w * 32 + rt * 16 + quad * 4;
#pragma unroll
        for (int ct = 0; ct < 8; ++ct) {
            int col = ct * 16 + lr;
#pragma unroll
            for (int reg = 0; reg < 4; ++reg) {
                int row = rb + reg;
                stage[row * 136 + col] = f2b(2.f * acc[rt][ct][reg] - ((row == col) ? 1.f : 0.f));
            }
        }
    }
    __syncthreads();
    unsigned short* Mo = L2m + ((size_t)(rel * Bk + b)) * Nn * Nn;
#pragma unroll
    for (int i = 0; i < 16; ++i) {
        int idx = tid + i * 256;
        int row = idx >> 5, c4 = (idx & 31) << 2;
        *(ushort4*)(Mo + row * Nn + c4) = *(ushort4*)&stage[row * 136 + c4];
    }
}

// ---------------- Chebyshev staging v2: one MFMA phase, T1 = L@X, T2 = L2m@X ----------------
template <int FIN>
__global__ __launch_bounds__(256) void cheb_v2(const unsigned short* __restrict__ Lb,
                                               const unsigned short* __restrict__ L2m,
                                               const float* __restrict__ xin,
                                               unsigned short* __restrict__ Xb) {
    constexpr int LDK = 136;
    __shared__ __align__(16) unsigned short Ls[128 * LDK];
    __shared__ __align__(16) unsigned short L2s[128 * LDK];
    __shared__ __align__(16) unsigned short XsT[32 * LDK];
    __shared__ __align__(16) unsigned short T1T[32 * LDK];
    __shared__ __align__(16) unsigned short T2T[32 * LDK];
    int z = blockIdx.y;
    int b = z & 31, rel = z >> 5;
    int c0 = blockIdx.x * 32;
    int tid = threadIdx.x;
    int w = tid >> 6, lane = tid & 63, quad = lane >> 4, lr = lane & 15;
    const unsigned short* Lp  = Lb  + ((size_t)(rel * Bk + b)) * Nn * Nn;
    const unsigned short* L2p = L2m + ((size_t)(rel * Bk + b)) * Nn * Nn;
    const float* Xp = xin + (size_t)b * Nn * FIN;
    const int ld6 = 6 * FIN;
    unsigned short* Xo = Xb + (size_t)b * Nn * ld6 + rel * 3 * FIN;

#pragma unroll
    for (int i = 0; i < 16; ++i) {
        int idx = tid + i * 256;
        int row = idx >> 5, col4 = (idx & 31) << 2;
        *(ushort4*)&Ls[row * LDK + col4]  = *(const ushort4*)(Lp  + row * Nn + col4);
        *(ushort4*)&L2s[row * LDK + col4] = *(const ushort4*)(L2p + row * Nn + col4);
    }
    {
        int node = tid >> 1, cb = (tid & 1) * 16;
        const float* xr = Xp + (size_t)node * FIN + c0 + cb;
        unsigned short* t0w = Xo + (size_t)node * ld6 + c0 + cb;
#pragma unroll
        for (int i = 0; i < 4; ++i) {
            float4 vv = *(const float4*)(xr + i * 4);
            ushort4 o;
            o.x = f2b(vv.x); o.y = f2b(vv.y); o.z = f2b(vv.z); o.w = f2b(vv.w);
            *(ushort4*)(t0w + i * 4) = o;
            XsT[(cb + i * 4 + 0) * LDK + node] = o.x;
            XsT[(cb + i * 4 + 1) * LDK + node] = o.y;
            XsT[(cb + i * 4 + 2) * LDK + node] = o.z;
            XsT[(cb + i * 4 + 3) * LDK + node] = o.w;
        }
    }
    __syncthreads();

    floatx4 acc1[2][2], acc2[2][2];
#pragma unroll
    for (int rt = 0; rt < 2; ++rt)
#pragma unroll
        for (int ct = 0; ct < 2; ++ct) {
            acc1[rt][ct] = (floatx4){0.f, 0.f, 0.f, 0.f};
            acc2[rt][ct] = (floatx4){0.f, 0.f, 0.f, 0.f};
        }
#pragma unroll
    for (int kc = 0; kc < 4; ++kc) {
        short8 a1[2], a2[2], bb[2];
#pragma unroll
        for (int rt = 0; rt < 2; ++rt) {
            a1[rt] = *(const short8*)&Ls[((w * 2 + rt) * 16 + lr) * LDK + kc * 32 + quad * 8];
            a2[rt] = *(const short8*)&L2s[((w * 2 + rt) * 16 + lr) * LDK + kc * 32 + quad * 8];
        }
#pragma unroll
        for (int ct = 0; ct < 2; ++ct)
            bb[ct] = *(const short8*)&XsT[(ct * 16 + lr) * LDK + kc * 32 + quad * 8];
#pragma unroll
        for (int rt = 0; rt < 2; ++rt)
#pragma unroll
            for (int ct = 0; ct < 2; ++ct) {
                acc1[rt][ct] = __builtin_amdgcn_mfma_f32_16x16x32_bf16(a1[rt], bb[ct], acc1[rt][ct], 0, 0, 0);
                acc2[rt][ct] = __builtin_amdgcn_mfma_f32_16x16x32_bf16(a2[rt], bb[ct], acc2[rt][ct], 0, 0, 0);
            }
    }
#pragma unroll
    for (int rt = 0; rt < 2; ++rt) {
        int rb = (w * 2 + rt) * 16 + quad * 4;
#pragma unroll
        for (int ct = 0; ct < 2; ++ct) {
            int col = ct * 16 + lr;
            ushort4 o1, o2;
            o1.x = f2b(acc1[rt][ct][0]); o1.y = f2b(acc1[rt][ct][1]);
            o1.z = f2b(acc1[rt][ct][2]); o1.w = f2b(acc1[rt][ct][3]);
            o2.x = f2b(acc2[rt][ct][0]); o2.y = f2b(acc2[rt][ct][1]);
            o2.z = f2b(acc2[rt][ct][2]); o2.w = f2b(acc2[rt][ct][3]);
            *(ushort4*)&T1T[col * LDK + rb] = o1;
            *(ushort4*)&T2T[col * LDK + rb] = o2;
        }
    }
    __syncthreads();
    {
        int node = tid >> 1, cb = (tid & 1) * 16;
        unsigned short* t1w = Xo + (size_t)node * ld6 + FIN + c0 + cb;
        unsigned short* t2w = Xo + (size_t)node * ld6 + 2 * FIN + c0 + cb;
#pragma unroll
        for (int i = 0; i < 4; ++i) {
            ushort4 o1, o2;
            o1.x = T1T[(cb + i * 4 + 0) * LDK + node];
            o1.y = T1T[(cb + i * 4 + 1) * LDK + node];
            o1.z = T1T[(cb + i * 4 + 2) * LDK + node];
            o1.w = T1T[(cb + i * 4 + 3) * LDK + node];
            o2.x = T2T[(cb + i * 4 + 0) * LDK + node];
            o2.y = T2T[(cb + i * 4 + 1) * LDK + node];
            o2.z = T2T[(cb + i * 4 + 2) * LDK + node];
            o2.w = T2T[(cb + i * 4 + 3) * LDK + node];
            *(ushort4*)(t1w + i * 4) = o1;
            *(ushort4*)(t2w + i * 4) = o2;
        }
    }
}

// ---------------- fc via bf16 MFMA + fused bias/mask/BN/relu (+optional max-pool) ----------------
template <int RT, bool POOL>
__global__ __launch_bounds__(256) void fc_mfma(const unsigned short* __restrict__ Xb,
                                               const unsigned short* __restrict__ Wt,
                                               const float* __restrict__ bias,
                                               const float* __restrict__ mask,
                                               const float* __restrict__ bnG,
                                               const float* __restrict__ bnB,
                                               const float* __restrict__ bnM,
                                               const float* __restrict__ bnV,
                                               float* __restrict__ out,
                                               float* __restrict__ pooled,
                                               int Kd, int F) {
    __shared__ __align__(16) unsigned short As[RT * 64 * 40];
    __shared__ __align__(16) unsigned short Bs[64 * 40];
    __shared__ float wmax[4][64];
    int tid = threadIdx.x;
    int w = tid >> 6, lane = tid & 63, quad = lane >> 4, lr = lane & 15;
    int row0 = blockIdx.y * (RT * 64), col0 = blockIdx.x * 64;

    floatx4 acc[RT][4];
#pragma unroll
    for (int rt = 0; rt < RT; ++rt)
#pragma unroll
        for (int ct = 0; ct < 4; ++ct) acc[rt][ct] = (floatx4){0.f, 0.f, 0.f, 0.f};

    int arow[RT], asub[RT];
#pragma unroll
    for (int i = 0; i < RT; ++i) { int ch = tid + i * 256; arow[i] = ch >> 2; asub[i] = ch & 3; }
    int brow = tid >> 2, bsub = tid & 3;

    for (int k0 = 0; k0 < Kd; k0 += 32) {
        short8 ra[RT];
#pragma unroll
        for (int i = 0; i < RT; ++i)
            ra[i] = *(const short8*)(Xb + (size_t)(row0 + arow[i]) * Kd + k0 + asub[i] * 8);
        short8 rb = *(const short8*)(Wt + (size_t)(col0 + brow) * Kd + k0 + bsub * 8);
        __syncthreads();
#pragma unroll
        for (int i = 0; i < RT; ++i)
            *(short8*)&As[arow[i] * 40 + asub[i] * 8] = ra[i];
        *(short8*)&Bs[brow * 40 + bsub * 8] = rb;
        __syncthreads();
        short8 a[RT], b[4];
#pragma unroll
        for (int rt = 0; rt < RT; ++rt)
            a[rt] = *(const short8*)&As[(w * RT * 16 + rt * 16 + lr) * 40 + quad * 8];
#pragma unroll
        for (int ct = 0; ct < 4; ++ct)
            b[ct] = *(const short8*)&Bs[(ct * 16 + lr) * 40 + quad * 8];
#pragma unroll
        for (int rt = 0; rt < RT; ++rt)
#pragma unroll
            for (int ct = 0; ct < 4; ++ct)
                acc[rt][ct] = __builtin_amdgcn_mfma_f32_16x16x32_bf16(a[rt], b[ct], acc[rt][ct], 0, 0, 0);
    }

    float cm[4] = {0.f, 0.f, 0.f, 0.f};
#pragma unroll
    for (int rt = 0; rt < RT; ++rt) {
        int rbase = row0 + w * RT * 16 + rt * 16 + quad * 4;
#pragma unroll
        for (int ct = 0; ct < 4; ++ct) {
            int col = col0 + ct * 16 + lr;
            float bi = bias[col];
            float sc = rsqrtf(bnV[col] + BN_EPS) * bnG[col];
            float bm = bnM[col], bb = bnB[col];
#pragma unroll
            for (int reg = 0; reg < 4; ++reg) {
                int row = rbase + reg;
                float h = acc[rt][ct][reg] + bi;
                h *= mask[row];
                h = (h - bm) * sc + bb;
                h = fmaxf(h, 0.f);
                if (POOL) cm[ct] = fmaxf(cm[ct], h);
                else      out[(size_t)row * F + col] = h;
            }
        }
    }
    if (POOL) {
#pragma unroll
        for (int ct = 0; ct < 4; ++ct) {
            cm[ct] = fmaxf(cm[ct], __shfl_xor(cm[ct], 16));
            cm[ct] = fmaxf(cm[ct], __shfl_xor(cm[ct], 32));
            if (quad == 0) wmax[w][ct * 16 + lr] = cm[ct];
        }
        __syncthreads();
        if (tid < 64) {
            float g = fmaxf(fmaxf(wmax[0][tid], wmax[1][tid]), fmaxf(wmax[2][tid], wmax[3][tid]));
            int b = blockIdx.y;
            pooled[(size_t)b * 512 + col0 + tid] = g;
        }
    }
}

// ---------------- final: out = pooled @ Wc + bc ----------------
__global__ __launch_bounds__(256) void cls_final(const float* __restrict__ pooled,
                                                 const float* __restrict__ Wc,
                                                 const float* __restrict__ bc,
                                                 float* __restrict__ out) {
    __shared__ float red[16][17];
    int b = blockIdx.x, tid = threadIdx.x;
    int o = tid & 15, slice = tid >> 4;
    float p = 0.f;
    if (o < 10) {
        for (int kk = 0; kk < 32; ++kk) {
            int k = slice * 32 + kk;
            p += pooled[(size_t)b * 512 + k] * Wc[(size_t)k * 10 + o];
        }
    }
    red[slice][o] = p;
    __syncthreads();
    if (tid < 10) {
        float sum = bc[tid];
        for (int sli = 0; sli < 16; ++sli) sum += red[sli][tid];
        out[(size_t)b * 10 + tid] = sum;
    }
}

extern "C" void kernel_launch(void* const* d_in, const int* in_sizes, int n_in,
                              void* d_out, int out_size, void* d_ws, size_t ws_size,
                              hipStream_t stream) {
    const float* x    = (const float*)d_in[0];
    const float* Ain  = (const float*)d_in[1];
    const float* mask = (const float*)d_in[2];
    const float* eW1  = (const float*)d_in[3];
    const float* eb1  = (const float*)d_in[4];
    const float* eW2  = (const float*)d_in[5];
    const float* eb2  = (const float*)d_in[6];
    const float* fW1  = (const float*)d_in[25];
    const float* fb1  = (const float*)d_in[26];
    const float* fW2  = (const float*)d_in[27];
    const float* fb2  = (const float*)d_in[28];

    float* ws = (float*)d_ws;
    float* uv = ws + OFF_UV;
    float* ap = ws + OFF_AP;
    unsigned short* Lb  = (unsigned short*)(ws + OFF_LB);
    unsigned short* L2m = (unsigned short*)(ws + OFF_L2M);
    float* h0 = ws + OFF_H0;
    float* h1 = ws + OFF_H1;
    float* pl = ws + OFF_POOL;
    float* Wc = ws + OFF_WC;
    float* bc = ws + OFF_BC;
    unsigned short* xb0 = (unsigned short*)(ws + OFF_XB0);
    unsigned short* Xb  = (unsigned short*)(ws + OFF_XB);
    unsigned short* Wt  = (unsigned short*)(ws + OFF_WT);

    prep_all<<<765, 256, 0, stream>>>((const float*)d_in[7], (const float*)d_in[13],
                                      (const float*)d_in[19], eW1, fW1, fb1, fW2, fb2, x,
                                      Wt, Wc, bc, xb0);

    uv_mfma<<<dim3(2, 32), 256, 0, stream>>>(xb0, Wt + WUV_OFS, eb1, uv);
    edge_sym<<<dim3(36, Bk), 256, 0, stream>>>(uv, eW2, eb2, mask, ap);
    adj_L2<<<64, 256, 0, stream>>>(ap, Ain, Lb, L2m);

    const float* xins[3] = {x, h0, h1};
    const unsigned short* Wts[3] = {Wt, Wt + 49152, Wt + 147456};
    const int Kds[3] = {768, 384, 1536};
    for (int li = 0; li < 3; ++li) {
        int base = 7 + li * 6;
        const float* gb = (const float*)d_in[base + 1];
        const float* gg = (const float*)d_in[base + 2];
        const float* gB = (const float*)d_in[base + 3];
        const float* gm = (const float*)d_in[base + 4];
        const float* gv = (const float*)d_in[base + 5];

        if (li == 0)      cheb_v2<128><<<dim3(4, 64), 256, 0, stream>>>(Lb, L2m, xins[li], Xb);
        else if (li == 1) cheb_v2<64><<<dim3(2, 64), 256, 0, stream>>>(Lb, L2m, xins[li], Xb);
        else              cheb_v2<256><<<dim3(8, 64), 256, 0, stream>>>(Lb, L2m, xins[li], Xb);

        if (li == 0)
            fc_mfma<1, false><<<dim3(1, 64), 256, 0, stream>>>(
                Xb, Wts[li], gb, mask, gg, gB, gm, gv, h0, nullptr, Kds[li], 64);
        else if (li == 1)
            fc_mfma<2, false><<<dim3(4, 32), 256, 0, stream>>>(
                Xb, Wts[li], gb, mask, gg, gB, gm, gv, h1, nullptr, Kds[li], 256);
        else
            fc_mfma<2, true><<<dim3(8, 32), 256, 0, stream>>>(
                Xb, Wts[li], gb, mask, gg, gB, gm, gv, nullptr, pl, Kds[li], 512);
    }

    cls_final<<<Bk, 256, 0, stream>>>(pl, Wc, bc, (float*)d_out);
}

// Round 8
// 242.589 us; speedup vs baseline: 1.0105x; 1.0105x over previous
//
#include <hip/hip_runtime.h>

// ---------------- constants ----------------
#define Bk 32      // batch
#define Nn 128     // nodes
#define Cc 128     // in channels
#define HE 64      // edge hidden
#define BN_EPS 1e-5f

typedef __attribute__((ext_vector_type(8))) short short8;
typedef __attribute__((ext_vector_type(4))) float floatx4;

// workspace offsets (floats)
#define OFF_UV   ((size_t)0)         // 524288  uv f32 [4096][128]
#define OFF_AP   ((size_t)524288)    // 524288  masked exp scores (upper-tri valid)
#define OFF_LB   ((size_t)1048576)   // 524288 f = bf16 L [2 rel][32 b][128][128]
#define OFF_H0   ((size_t)1572864)   // 262144
#define OFF_H1   ((size_t)1835008)   // 1048576
#define OFF_POOL ((size_t)2883584)   // 16384
#define OFF_WC   ((size_t)2899968)   // 5120
#define OFF_BC   ((size_t)2905088)   // 16
#define OFF_XB0  ((size_t)2905104)   // 262144 f = bf16 x
#define OFF_XB   ((size_t)3167248)   // 3145728 f = bf16 Xcat [4096][1536max]
#define OFF_WT   ((size_t)6312976)   // 475136 f (Wt0,Wt1,Wt2,Wuv)
#define OFF_L2M  ((size_t)6788112)   // 524288 f = bf16 L2m=2L^2-I [2 rel][32 b][128][128]
#define WUV_OFS  933888              // ushort offset of Wuv inside WT region

__device__ __forceinline__ unsigned short f2b(float f) {
    unsigned int x = __float_as_uint(f);
    unsigned int r = x + 0x7FFFu + ((x >> 16) & 1u);
    return (unsigned short)(r >> 16);
}

// ---------------- prep: weight transposes (bf16), Wuv, folded classifier, x->bf16 ----------------
__global__ __launch_bounds__(256) void prep_all(const float* __restrict__ W0,
                                                const float* __restrict__ W1,
                                                const float* __restrict__ W2,
                                                const float* __restrict__ eW1,
                                                const float* __restrict__ fW1,
                                                const float* __restrict__ fb1,
                                                const float* __restrict__ fW2,
                                                const float* __restrict__ fb2,
                                                const float* __restrict__ x,
                                                unsigned short* __restrict__ Wt,
                                                float* __restrict__ Wc,
                                                float* __restrict__ bc,
                                                unsigned short* __restrict__ xb0) {
    __shared__ unsigned short Ts[64][65];
    int bid = blockIdx.x, tid = threadIdx.x;
    if (bid < 228) {
        const float* src; unsigned short* dst; int N, ldK, k0, n0;
        if (bid < 12)      { src = W0; dst = Wt;          N = 64;  ldK = 768;  k0 = bid * 64;        n0 = 0; }
        else if (bid < 36) { int t = bid - 12; src = W1; dst = Wt + 49152;  N = 256; ldK = 384;  k0 = (t % 6) * 64;  n0 = (t / 6) * 64; }
        else               { int t = bid - 36; src = W2; dst = Wt + 147456; N = 512; ldK = 1536; k0 = (t % 24) * 64; n0 = (t / 24) * 64; }
#pragma unroll
        for (int p = 0; p < 16; ++p) {
            int e = tid + p * 256; int r = e >> 6, c = e & 63;
            Ts[r][c] = f2b(src[(size_t)(k0 + r) * N + n0 + c]);
        }
        __syncthreads();
#pragma unroll
        for (int p = 0; p < 16; ++p) {
            int e = tid + p * 256; int n = e >> 6, k = e & 63;
            dst[(size_t)(n0 + n) * ldK + k0 + k] = Ts[k][n];
        }
        return;
    }
    if (bid < 232) {
        int tt = bid - 228;
        int half = tt >> 1, kt = tt & 1;
        int k0 = kt * 64;
        unsigned short* Wuv = Wt + WUV_OFS;
#pragma unroll
        for (int p = 0; p < 16; ++p) {
            int e = tid + p * 256; int r = e >> 6, c = e & 63;
            Ts[r][c] = f2b(eW1[(size_t)(half * 128 + k0 + r) * 64 + c]);
        }
        __syncthreads();
#pragma unroll
        for (int p = 0; p < 16; ++p) {
            int e = tid + p * 256; int n = e >> 6, k = e & 63;
            Wuv[(size_t)(half * 64 + n) * 128 + k0 + k] = Ts[k][n];
        }
        return;
    }
    if (bid < 253) {
        int e = (bid - 232) * 256 + tid;
        if (e < 5120) {
            int i = e / 10, j = e - i * 10;
            float acc = 0.f;
            for (int h = 0; h < 256; ++h) acc += fW1[(size_t)i * 256 + h] * fW2[(size_t)h * 10 + j];
            Wc[e] = acc;
        } else if (e < 5130) {
            int j = e - 5120;
            float acc = fb2[j];
            for (int h = 0; h < 256; ++h) acc += fb1[h] * fW2[(size_t)h * 10 + j];
            bc[j] = acc;
        }
        return;
    }
    {
        int idx = (bid - 253) * 256 + tid;
        float4 vv = ((const float4*)x)[idx];
        ushort4 o;
        o.x = f2b(vv.x); o.y = f2b(vv.y); o.z = f2b(vv.z); o.w = f2b(vv.w);
        ((ushort4*)xb0)[idx] = o;
    }
}

// ---------------- uv = x @ Wuv (+eb1 on u cols) via bf16 MFMA ----------------
__global__ __launch_bounds__(256) void uv_mfma(const unsigned short* __restrict__ xb0,
                                               const unsigned short* __restrict__ Wuv,
                                               const float* __restrict__ eb1,
                                               float* __restrict__ uv) {
    __shared__ __align__(16) unsigned short As[128 * 40];
    __shared__ __align__(16) unsigned short Bs[64 * 40];
    int tid = threadIdx.x;
    int w = tid >> 6, lane = tid & 63, quad = lane >> 4, lr = lane & 15;
    int row0 = blockIdx.y * 128, col0 = blockIdx.x * 64;
    floatx4 acc[2][4];
#pragma unroll
    for (int rt = 0; rt < 2; ++rt)
#pragma unroll
        for (int ct = 0; ct < 4; ++ct) acc[rt][ct] = (floatx4){0.f, 0.f, 0.f, 0.f};
    int arow[2], asub[2];
#pragma unroll
    for (int i = 0; i < 2; ++i) { int ch = tid + i * 256; arow[i] = ch >> 2; asub[i] = ch & 3; }
    int brow = tid >> 2, bsub = tid & 3;
    for (int k0 = 0; k0 < 128; k0 += 32) {
        short8 ra[2];
#pragma unroll
        for (int i = 0; i < 2; ++i)
            ra[i] = *(const short8*)(xb0 + (size_t)(row0 + arow[i]) * 128 + k0 + asub[i] * 8);
        short8 rb = *(const short8*)(Wuv + (size_t)(col0 + brow) * 128 + k0 + bsub * 8);
        __syncthreads();
#pragma unroll
        for (int i = 0; i < 2; ++i) *(short8*)&As[arow[i] * 40 + asub[i] * 8] = ra[i];
        *(short8*)&Bs[brow * 40 + bsub * 8] = rb;
        __syncthreads();
        short8 a[2], b[4];
#pragma unroll
        for (int rt = 0; rt < 2; ++rt)
            a[rt] = *(const short8*)&As[(w * 32 + rt * 16 + lr) * 40 + quad * 8];
#pragma unroll
        for (int ct = 0; ct < 4; ++ct)
            b[ct] = *(const short8*)&Bs[(ct * 16 + lr) * 40 + quad * 8];
#pragma unroll
        for (int rt = 0; rt < 2; ++rt)
#pragma unroll
            for (int ct = 0; ct < 4; ++ct)
                acc[rt][ct] = __builtin_amdgcn_mfma_f32_16x16x32_bf16(a[rt], b[ct], acc[rt][ct], 0, 0, 0);
    }
#pragma unroll
    for (int rt = 0; rt < 2; ++rt) {
        int rbase = row0 + w * 32 + rt * 16 + quad * 4;
#pragma unroll
        for (int ct = 0; ct < 4; ++ct) {
            int col = col0 + ct * 16 + lr;
            float bi = (col < 64) ? eb1[col] : 0.f;
#pragma unroll
            for (int reg = 0; reg < 4; ++reg)
                uv[(size_t)(rbase + reg) * 128 + col] = acc[rt][ct][reg] + bi;
        }
    }
}

// ---------------- symmetric masked-exp edge scores (upper-tri tile pairs only) ----------------
__global__ __launch_bounds__(256) void edge_sym(const float* __restrict__ uv,
                                                const float* __restrict__ eW2,
                                                const float* __restrict__ eb2,
                                                const float* __restrict__ mask,
                                                float* __restrict__ ap) {
    __shared__ __align__(16) float ui[16][68], vi[16][68], uj[16][68], vj[16][68];
    __shared__ __align__(16) float w2[64];
    int t = blockIdx.x, b = blockIdx.y;
    int ti = 0, rem = t;
    for (;;) { int w = 8 - ti; if (rem < w) break; rem -= w; ++ti; }
    int tj = ti + rem;
    int i0 = ti * 16, j0 = tj * 16;
    int tid = threadIdx.x;
    int r = tid >> 4, c4 = (tid & 15) * 4;
    const float* uvb = uv + (size_t)b * Nn * 128;
    *(float4*)&ui[r][c4] = *(const float4*)(uvb + (size_t)(i0 + r) * 128 + c4);
    *(float4*)&vi[r][c4] = *(const float4*)(uvb + (size_t)(i0 + r) * 128 + 64 + c4);
    *(float4*)&uj[r][c4] = *(const float4*)(uvb + (size_t)(j0 + r) * 128 + c4);
    *(float4*)&vj[r][c4] = *(const float4*)(uvb + (size_t)(j0 + r) * 128 + 64 + c4);
    if (tid < 64) w2[tid] = eW2[tid];
    __syncthreads();
    int il = tid >> 4, jl = tid & 15;
    int gi = i0 + il, gj = j0 + jl;
    if (gj <= gi) return;
    float d = 0.f;
#pragma unroll
    for (int h4 = 0; h4 < 16; ++h4) {
        float4 a1 = *(const float4*)&ui[il][h4 * 4];
        float4 b1 = *(const float4*)&vj[jl][h4 * 4];
        float4 a2 = *(const float4*)&uj[jl][h4 * 4];
        float4 b2 = *(const float4*)&vi[il][h4 * 4];
        float4 ww = *(const float4*)&w2[h4 * 4];
        d += (fmaxf(a1.x + b1.x, 0.f) + fmaxf(a2.x + b2.x, 0.f)) * ww.x
           + (fmaxf(a1.y + b1.y, 0.f) + fmaxf(a2.y + b2.y, 0.f)) * ww.y
           + (fmaxf(a1.z + b1.z, 0.f) + fmaxf(a2.z + b2.z, 0.f)) * ww.z
           + (fmaxf(a1.w + b1.w, 0.f) + fmaxf(a2.w + b2.w, 0.f)) * ww.w;
    }
    float p = 0.5f * d + eb2[0];
    float mi = mask[b * Nn + gi], mj = mask[b * Nn + gj];
    float val = (mi != 0.f && mj != 0.f) ? expf(fminf(p, 80.f)) : 0.f;
    ap[((size_t)(b * Nn + gi)) * Nn + gj] = val;
}

// ---------------- merged adjacency -> L (bf16) AND L2m = 2L^2 - I (bf16 MFMA) ----------------
__global__ __launch_bounds__(256) void adj_L2(const float* __restrict__ ap,
                                              const float* __restrict__ A,
                                              unsigned short* __restrict__ Lb,
                                              unsigned short* __restrict__ L2m) {
    __shared__ float apS[128][129];
    __shared__ __align__(16) unsigned short LbS[128 * 136];
    __shared__ __align__(16) unsigned short LbT[128 * 136];
    __shared__ float part[256];
    __shared__ float sc1[128], t1S[128], sc2[128];
    int bid = blockIdx.x, tid = threadIdx.x;
    int w = tid >> 6, lane = tid & 63, quad = lane >> 4, lr = lane & 15;
    int rel, b;
    if (bid < 32) {
        rel = 1; b = bid;
        const float* apg = ap + (size_t)b * Nn * Nn;
        for (int k = 0; k < 64; ++k) {
            int idx = tid + k * 256;
            int i = idx >> 7, j = idx & 127;
            float g = apg[idx];
            apS[i][j] = (j > i) ? g : 0.f;
        }
        __syncthreads();
        {
            int row = tid >> 1, half = tid & 1;
            float s0 = 0.f;
            for (int j = half * 64; j < half * 64 + 64; ++j) s0 += apS[row][j];
            part[tid] = s0;
        }
        __syncthreads();
        if (tid < 128) {
            float rsum = part[tid * 2] + part[tid * 2 + 1];
            sc1[tid] = (rsum == 0.f) ? 1.f : (1.f / rsum);
            t1S[tid] = (rsum == 0.f) ? 0.f : 1.f;
        }
        __syncthreads();
        {
            int col = tid >> 1, half = tid & 1;
            float s0 = 0.f;
            for (int j = half * 64; j < half * 64 + 64; ++j) s0 += apS[j][col] * sc1[j];
            part[tid] = s0;
        }
        __syncthreads();
        if (tid < 128) sc2[tid] = rsqrtf(t1S[tid] + part[tid * 2] + part[tid * 2 + 1] + 1e-5f);
        __syncthreads();
        unsigned short* Lo = Lb + ((size_t)(Bk + b)) * Nn * Nn;
        for (int k = 0; k < 64; ++k) {
            int idx = tid + k * 256;
            int i = idx >> 7, j = idx & 127;
            float an = apS[i][j] * sc1[i] + apS[j][i] * sc1[j];
            unsigned short hv = f2b(sc2[i] * an * sc2[j]);
            LbS[i * 136 + j] = hv;          // symmetric
            Lo[idx] = hv;
        }
    } else {
        rel = 0; b = bid - 32;
        const float* Ar = A + (size_t)b * Nn * Nn;
        {
            int j = tid & 127, half = tid >> 7;
            float sum = 0.f;
            for (int i = half * 64; i < half * 64 + 64; ++i) sum += Ar[i * Nn + j];
            part[tid] = sum;
        }
        __syncthreads();
        if (tid < 128) sc2[tid] = rsqrtf(part[tid] + part[tid + 128] + 1e-5f);
        __syncthreads();
        unsigned short* Lo = Lb + (size_t)b * Nn * Nn;
        for (int k = 0; k < 64; ++k) {
            int idx = tid + k * 256;
            int i = idx >> 7, j = idx & 127;
            unsigned short hv = f2b(sc2[i] * Ar[idx] * sc2[j]);
            LbS[i * 136 + j] = hv;
            LbT[j * 136 + i] = hv;
            Lo[idx] = hv;
        }
    }
    __syncthreads();
    const unsigned short* Bsrc = (bid < 32) ? LbS : LbT;
    floatx4 acc[2][8];
#pragma unroll
    for (int rt = 0; rt < 2; ++rt)
#pragma unroll
        for (int ct = 0; ct < 8; ++ct) acc[rt][ct] = (floatx4){0.f, 0.f, 0.f, 0.f};
#pragma unroll
    for (int kc = 0; kc < 4; ++kc) {
        short8 a[2], bb[8];
#pragma unroll
        for (int rt = 0; rt < 2; ++rt)
            a[rt] = *(const short8*)&LbS[((w * 2 + rt) * 16 + lr) * 136 + kc * 32 + quad * 8];
#pragma unroll
        for (int ct = 0; ct < 8; ++ct)
            bb[ct] = *(const short8*)&Bsrc[(ct * 16 + lr) * 136 + kc * 32 + quad * 8];
#pragma unroll
        for (int rt = 0; rt < 2; ++rt)
#pragma unroll
            for (int ct = 0; ct < 8; ++ct)
                acc[rt][ct] = __builtin_amdgcn_mfma_f32_16x16x32_bf16(a[rt], bb[ct], acc[rt][ct], 0, 0, 0);
    }
    unsigned short* stage = (unsigned short*)&apS[0][0];
#pragma unroll
    for (int rt = 0; rt < 2; ++rt) {
        int rb = w * 32 + rt * 16 + quad * 4;
#pragma unroll
        for (int ct = 0; ct < 8; ++ct) {
            int col = ct * 16 + lr;
#pragma unroll
            for (int reg = 0; reg < 4; ++reg) {
                int row = rb + reg;
                stage[row * 136 + col] = f2b(2.f * acc[rt][ct][reg] - ((row == col) ? 1.f : 0.f));
            }
        }
    }
    __syncthreads();
    unsigned short* Mo = L2m + ((size_t)(rel * Bk + b)) * Nn * Nn;
#pragma unroll
    for (int i = 0; i < 16; ++i) {
        int idx = tid + i * 256;
        int row = idx >> 5, c4 = (idx & 31) << 2;
        *(ushort4*)(Mo + row * Nn + c4) = *(ushort4*)&stage[row * 136 + c4];
    }
}

// ---------------- Chebyshev staging v3: L/L2m A-frags direct from global (registers) ----------------
// LDS only holds X^T / T1^T / T2^T (26 KB). T1 = L@X, T2 = L2m@X in one MFMA loop.
template <int FIN>
__global__ __launch_bounds__(256) void cheb_v3(const unsigned short* __restrict__ Lb,
                                               const unsigned short* __restrict__ L2m,
                                               const float* __restrict__ xin,
                                               unsigned short* __restrict__ Xb) {
    constexpr int LDK = 136;
    __shared__ __align__(16) unsigned short XsT[32 * LDK];
    __shared__ __align__(16) unsigned short T1T[32 * LDK];
    __shared__ __align__(16) unsigned short T2T[32 * LDK];
    int z = blockIdx.y;
    int b = z & 31, rel = z >> 5;
    int c0 = blockIdx.x * 32;
    int tid = threadIdx.x;
    int w = tid >> 6, lane = tid & 63, quad = lane >> 4, lr = lane & 15;
    const unsigned short* Lp  = Lb  + ((size_t)(rel * Bk + b)) * Nn * Nn;
    const unsigned short* L2p = L2m + ((size_t)(rel * Bk + b)) * Nn * Nn;
    const float* Xp = xin + (size_t)b * Nn * FIN;
    const int ld6 = 6 * FIN;
    unsigned short* Xo = Xb + (size_t)b * Nn * ld6 + rel * 3 * FIN;

    // ---- preload A-frags from global (row-private per wave; L2-resident) ----
    short8 aL[2][4], aM[2][4];
#pragma unroll
    for (int rt = 0; rt < 2; ++rt) {
        int row = w * 32 + rt * 16 + lr;
#pragma unroll
        for (int kc = 0; kc < 4; ++kc) {
            aL[rt][kc] = *(const short8*)(Lp  + (size_t)row * Nn + kc * 32 + quad * 8);
            aM[rt][kc] = *(const short8*)(L2p + (size_t)row * Nn + kc * 32 + quad * 8);
        }
    }
    // ---- X col-slice -> XsT (transposed bf16) + T0 writeback ----
    {
        int node = tid >> 1, cb = (tid & 1) * 16;
        const float* xr = Xp + (size_t)node * FIN + c0 + cb;
        unsigned short* t0w = Xo + (size_t)node * ld6 + c0 + cb;
#pragma unroll
        for (int i = 0; i < 4; ++i) {
            float4 vv = *(const float4*)(xr + i * 4);
            ushort4 o;
            o.x = f2b(vv.x); o.y = f2b(vv.y); o.z = f2b(vv.z); o.w = f2b(vv.w);
            *(ushort4*)(t0w + i * 4) = o;
            XsT[(cb + i * 4 + 0) * LDK + node] = o.x;
            XsT[(cb + i * 4 + 1) * LDK + node] = o.y;
            XsT[(cb + i * 4 + 2) * LDK + node] = o.z;
            XsT[(cb + i * 4 + 3) * LDK + node] = o.w;
        }
    }
    __syncthreads();

    floatx4 acc1[2][2], acc2[2][2];
#pragma unroll
    for (int rt = 0; rt < 2; ++rt)
#pragma unroll
        for (int ct = 0; ct < 2; ++ct) {
            acc1[rt][ct] = (floatx4){0.f, 0.f, 0.f, 0.f};
            acc2[rt][ct] = (floatx4){0.f, 0.f, 0.f, 0.f};
        }
#pragma unroll
    for (int kc = 0; kc < 4; ++kc) {
        short8 bb[2];
#pragma unroll
        for (int ct = 0; ct < 2; ++ct)
            bb[ct] = *(const short8*)&XsT[(ct * 16 + lr) * LDK + kc * 32 + quad * 8];
#pragma unroll
        for (int rt = 0; rt < 2; ++rt)
#pragma unroll
            for (int ct = 0; ct < 2; ++ct) {
                acc1[rt][ct] = __builtin_amdgcn_mfma_f32_16x16x32_bf16(aL[rt][kc], bb[ct], acc1[rt][ct], 0, 0, 0);
                acc2[rt][ct] = __builtin_amdgcn_mfma_f32_16x16x32_bf16(aM[rt][kc], bb[ct], acc2[rt][ct], 0, 0, 0);
            }
    }
#pragma unroll
    for (int rt = 0; rt < 2; ++rt) {
        int rb = (w * 2 + rt) * 16 + quad * 4;
#pragma unroll
        for (int ct = 0; ct < 2; ++ct) {
            int col = ct * 16 + lr;
            ushort4 o1, o2;
            o1.x = f2b(acc1[rt][ct][0]); o1.y = f2b(acc1[rt][ct][1]);
            o1.z = f2b(acc1[rt][ct][2]); o1.w = f2b(acc1[rt][ct][3]);
            o2.x = f2b(acc2[rt][ct][0]); o2.y = f2b(acc2[rt][ct][1]);
            o2.z = f2b(acc2[rt][ct][2]); o2.w = f2b(acc2[rt][ct][3]);
            *(ushort4*)&T1T[col * LDK + rb] = o1;
            *(ushort4*)&T2T[col * LDK + rb] = o2;
        }
    }
    __syncthreads();
    {
        int node = tid >> 1, cb = (tid & 1) * 16;
        unsigned short* t1w = Xo + (size_t)node * ld6 + FIN + c0 + cb;
        unsigned short* t2w = Xo + (size_t)node * ld6 + 2 * FIN + c0 + cb;
#pragma unroll
        for (int i = 0; i < 4; ++i) {
            ushort4 o1, o2;
            o1.x = T1T[(cb + i * 4 + 0) * LDK + node];
            o1.y = T1T[(cb + i * 4 + 1) * LDK + node];
            o1.z = T1T[(cb + i * 4 + 2) * LDK + node];
            o1.w = T1T[(cb + i * 4 + 3) * LDK + node];
            o2.x = T2T[(cb + i * 4 + 0) * LDK + node];
            o2.y = T2T[(cb + i * 4 + 1) * LDK + node];
            o2.z = T2T[(cb + i * 4 + 2) * LDK + node];
            o2.w = T2T[(cb + i * 4 + 3) * LDK + node];
            *(ushort4*)(t1w + i * 4) = o1;
            *(ushort4*)(t2w + i * 4) = o2;
        }
    }
}

// ---------------- fc via bf16 MFMA + fused bias/mask/BN/relu (+optional max-pool) ----------------
template <int RT, bool POOL>
__global__ __launch_bounds__(256) void fc_mfma(const unsigned short* __restrict__ Xb,
                                               const unsigned short* __restrict__ Wt,
                                               const float* __restrict__ bias,
                                               const float* __restrict__ mask,
                                               const float* __restrict__ bnG,
                                               const float* __restrict__ bnB,
                                               const float* __restrict__ bnM,
                                               const float* __restrict__ bnV,
                                               float* __restrict__ out,
                                               float* __restrict__ pooled,
                                               int Kd, int F) {
    __shared__ __align__(16) unsigned short As[RT * 64 * 40];
    __shared__ __align__(16) unsigned short Bs[64 * 40];
    __shared__ float wmax[4][64];
    int tid = threadIdx.x;
    int w = tid >> 6, lane = tid & 63, quad = lane >> 4, lr = lane & 15;
    int row0 = blockIdx.y * (RT * 64), col0 = blockIdx.x * 64;

    floatx4 acc[RT][4];
#pragma unroll
    for (int rt = 0; rt < RT; ++rt)
#pragma unroll
        for (int ct = 0; ct < 4; ++ct) acc[rt][ct] = (floatx4){0.f, 0.f, 0.f, 0.f};

    int arow[RT], asub[RT];
#pragma unroll
    for (int i = 0; i < RT; ++i) { int ch = tid + i * 256; arow[i] = ch >> 2; asub[i] = ch & 3; }
    int brow = tid >> 2, bsub = tid & 3;

    for (int k0 = 0; k0 < Kd; k0 += 32) {
        short8 ra[RT];
#pragma unroll
        for (int i = 0; i < RT; ++i)
            ra[i] = *(const short8*)(Xb + (size_t)(row0 + arow[i]) * Kd + k0 + asub[i] * 8);
        short8 rb = *(const short8*)(Wt + (size_t)(col0 + brow) * Kd + k0 + bsub * 8);
        __syncthreads();
#pragma unroll
        for (int i = 0; i < RT; ++i)
            *(short8*)&As[arow[i] * 40 + asub[i] * 8] = ra[i];
        *(short8*)&Bs[brow * 40 + bsub * 8] = rb;
        __syncthreads();
        short8 a[RT], b[4];
#pragma unroll
        for (int rt = 0; rt < RT; ++rt)
            a[rt] = *(const short8*)&As[(w * RT * 16 + rt * 16 + lr) * 40 + quad * 8];
#pragma unroll
        for (int ct = 0; ct < 4; ++ct)
            b[ct] = *(const short8*)&Bs[(ct * 16 + lr) * 40 + quad * 8];
#pragma unroll
        for (int rt = 0; rt < RT; ++rt)
#pragma unroll
            for (int ct = 0; ct < 4; ++ct)
                acc[rt][ct] = __builtin_amdgcn_mfma_f32_16x16x32_bf16(a[rt], b[ct], acc[rt][ct], 0, 0, 0);
    }

    float cm[4] = {0.f, 0.f, 0.f, 0.f};
#pragma unroll
    for (int rt = 0; rt < RT; ++rt) {
        int rbase = row0 + w * RT * 16 + rt * 16 + quad * 4;
#pragma unroll
        for (int ct = 0; ct < 4; ++ct) {
            int col = col0 + ct * 16 + lr;
            float bi = bias[col];
            float sc = rsqrtf(bnV[col] + BN_EPS) * bnG[col];
            float bm = bnM[col], bb = bnB[col];
#pragma unroll
            for (int reg = 0; reg < 4; ++reg) {
                int row = rbase + reg;
                float h = acc[rt][ct][reg] + bi;
                h *= mask[row];
                h = (h - bm) * sc + bb;
                h = fmaxf(h, 0.f);
                if (POOL) cm[ct] = fmaxf(cm[ct], h);
                else      out[(size_t)row * F + col] = h;
            }
        }
    }
    if (POOL) {
#pragma unroll
        for (int ct = 0; ct < 4; ++ct) {
            cm[ct] = fmaxf(cm[ct], __shfl_xor(cm[ct], 16));
            cm[ct] = fmaxf(cm[ct], __shfl_xor(cm[ct], 32));
            if (quad == 0) wmax[w][ct * 16 + lr] = cm[ct];
        }
        __syncthreads();
        if (tid < 64) {
            float g = fmaxf(fmaxf(wmax[0][tid], wmax[1][tid]), fmaxf(wmax[2][tid], wmax[3][tid]));
            int b = blockIdx.y;
            pooled[(size_t)b * 512 + col0 + tid] = g;
        }
    }
}

// ---------------- final: out = pooled @ Wc + bc ----------------
__global__ __launch_bounds__(256) void cls_final(const float* __restrict__ pooled,
                                                 const float* __restrict__ Wc,
                                                 const float* __restrict__ bc,
                                                 float* __restrict__ out) {
    __shared__ float red[16][17];
    int b = blockIdx.x, tid = threadIdx.x;
    int o = tid & 15, slice = tid >> 4;
    float p = 0.f;
    if (o < 10) {
        for (int kk = 0; kk < 32; ++kk) {
            int k = slice * 32 + kk;
            p += pooled[(size_t)b * 512 + k] * Wc[(size_t)k * 10 + o];
        }
    }
    red[slice][o] = p;
    __syncthreads();
    if (tid < 10) {
        float sum = bc[tid];
        for (int sli = 0; sli < 16; ++sli) sum += red[sli][tid];
        out[(size_t)b * 10 + tid] = sum;
    }
}

extern "C" void kernel_launch(void* const* d_in, const int* in_sizes, int n_in,
                              void* d_out, int out_size, void* d_ws, size_t ws_size,
                              hipStream_t stream) {
    const float* x    = (const float*)d_in[0];
    const float* Ain  = (const float*)d_in[1];
    const float* mask = (const float*)d_in[2];
    const float* eW1  = (const float*)d_in[3];
    const float* eb1  = (const float*)d_in[4];
    const float* eW2  = (const float*)d_in[5];
    const float* eb2  = (const float*)d_in[6];
    const float* fW1  = (const float*)d_in[25];
    const float* fb1  = (const float*)d_in[26];
    const float* fW2  = (const float*)d_in[27];
    const float* fb2  = (const float*)d_in[28];

    float* ws = (float*)d_ws;
    float* uv = ws + OFF_UV;
    float* ap = ws + OFF_AP;
    unsigned short* Lb  = (unsigned short*)(ws + OFF_LB);
    unsigned short* L2m = (unsigned short*)(ws + OFF_L2M);
    float* h0 = ws + OFF_H0;
    float* h1 = ws + OFF_H1;
    float* pl = ws + OFF_POOL;
    float* Wc = ws + OFF_WC;
    float* bc = ws + OFF_BC;
    unsigned short* xb0 = (unsigned short*)(ws + OFF_XB0);
    unsigned short* Xb  = (unsigned short*)(ws + OFF_XB);
    unsigned short* Wt  = (unsigned short*)(ws + OFF_WT);

    prep_all<<<765, 256, 0, stream>>>((const float*)d_in[7], (const float*)d_in[13],
                                      (const float*)d_in[19], eW1, fW1, fb1, fW2, fb2, x,
                                      Wt, Wc, bc, xb0);

    uv_mfma<<<dim3(2, 32), 256, 0, stream>>>(xb0, Wt + WUV_OFS, eb1, uv);
    edge_sym<<<dim3(36, Bk), 256, 0, stream>>>(uv, eW2, eb2, mask, ap);
    adj_L2<<<64, 256, 0, stream>>>(ap, Ain, Lb, L2m);

    const float* xins[3] = {x, h0, h1};
    const unsigned short* Wts[3] = {Wt, Wt + 49152, Wt + 147456};
    const int Kds[3] = {768, 384, 1536};
    for (int li = 0; li < 3; ++li) {
        int base = 7 + li * 6;
        const float* gb = (const float*)d_in[base + 1];
        const float* gg = (const float*)d_in[base + 2];
        const float* gB = (const float*)d_in[base + 3];
        const float* gm = (const float*)d_in[base + 4];
        const float* gv = (const float*)d_in[base + 5];

        if (li == 0)      cheb_v3<128><<<dim3(4, 64), 256, 0, stream>>>(Lb, L2m, xins[li], Xb);
        else if (li == 1) cheb_v3<64><<<dim3(2, 64), 256, 0, stream>>>(Lb, L2m, xins[li], Xb);
        else              cheb_v3<256><<<dim3(8, 64), 256, 0, stream>>>(Lb, L2m, xins[li], Xb);

        if (li == 0)
            fc_mfma<1, false><<<dim3(1, 64), 256, 0, stream>>>(
                Xb, Wts[li], gb, mask, gg, gB, gm, gv, h0, nullptr, Kds[li], 64);
        else if (li == 1)
            fc_mfma<2, false><<<dim3(4, 32), 256, 0, stream>>>(
                Xb, Wts[li], gb, mask, gg, gB, gm, gv, h1, nullptr, Kds[li], 256);
        else
            fc_mfma<2, true><<<dim3(8, 32), 256, 0, stream>>>(
                Xb, Wts[li], gb, mask, gg, gB, gm, gv, nullptr, pl, Kds[li], 512);
    }

    cls_final<<<Bk, 256, 0, stream>>>(pl, Wc, bc, (float*)d_out);
}

// Round 9
// 230.316 us; speedup vs baseline: 1.0643x; 1.0533x over previous
//
#include <hip/hip_runtime.h>

// ---------------- constants ----------------
#define Bk 32      // batch
#define Nn 128     // nodes
#define Cc 128     // in channels
#define HE 64      // edge hidden
#define BN_EPS 1e-5f

typedef __attribute__((ext_vector_type(8))) short short8;
typedef __attribute__((ext_vector_type(4))) float floatx4;

// workspace offsets (floats)
#define OFF_UV   ((size_t)0)         // 524288  uv f32 [4096][128]
#define OFF_AP   ((size_t)524288)    // 524288  masked exp scores (upper-tri valid)
#define OFF_LB   ((size_t)1048576)   // 524288 f = bf16 L [2 rel][32 b][128][128]
#define OFF_H0   ((size_t)1572864)   // 262144
#define OFF_H1   ((size_t)1835008)   // 1048576
#define OFF_WC   ((size_t)2899968)   // 5120
#define OFF_BC   ((size_t)2905088)   // 16
#define OFF_XB0  ((size_t)2905104)   // 262144 f = bf16 x
#define OFF_XB   ((size_t)3167248)   // 3145728 f = bf16 Xcat [4096][1536max]
#define OFF_WT   ((size_t)6312976)   // 475136 f (Wt0,Wt1,Wt2,Wuv)
#define WUV_OFS  933888              // ushort offset of Wuv inside WT region

__device__ __forceinline__ unsigned short f2b(float f) {
    unsigned int x = __float_as_uint(f);
    unsigned int r = x + 0x7FFFu + ((x >> 16) & 1u);
    return (unsigned short)(r >> 16);
}

// ---------------- prep: weight transposes (bf16), Wuv, folded classifier, x->bf16 ----------------
__global__ __launch_bounds__(256) void prep_all(const float* __restrict__ W0,
                                                const float* __restrict__ W1,
                                                const float* __restrict__ W2,
                                                const float* __restrict__ eW1,
                                                const float* __restrict__ fW1,
                                                const float* __restrict__ fb1,
                                                const float* __restrict__ fW2,
                                                const float* __restrict__ fb2,
                                                const float* __restrict__ x,
                                                unsigned short* __restrict__ Wt,
                                                float* __restrict__ Wc,
                                                float* __restrict__ bc,
                                                unsigned short* __restrict__ xb0) {
    __shared__ unsigned short Ts[64][65];
    int bid = blockIdx.x, tid = threadIdx.x;
    if (bid < 228) {
        const float* src; unsigned short* dst; int N, ldK, k0, n0;
        if (bid < 12)      { src = W0; dst = Wt;          N = 64;  ldK = 768;  k0 = bid * 64;        n0 = 0; }
        else if (bid < 36) { int t = bid - 12; src = W1; dst = Wt + 49152;  N = 256; ldK = 384;  k0 = (t % 6) * 64;  n0 = (t / 6) * 64; }
        else               { int t = bid - 36; src = W2; dst = Wt + 147456; N = 512; ldK = 1536; k0 = (t % 24) * 64; n0 = (t / 24) * 64; }
#pragma unroll
        for (int p = 0; p < 16; ++p) {
            int e = tid + p * 256; int r = e >> 6, c = e & 63;
            Ts[r][c] = f2b(src[(size_t)(k0 + r) * N + n0 + c]);
        }
        __syncthreads();
#pragma unroll
        for (int p = 0; p < 16; ++p) {
            int e = tid + p * 256; int n = e >> 6, k = e & 63;
            dst[(size_t)(n0 + n) * ldK + k0 + k] = Ts[k][n];
        }
        return;
    }
    if (bid < 232) {
        int tt = bid - 228;
        int half = tt >> 1, kt = tt & 1;
        int k0 = kt * 64;
        unsigned short* Wuv = Wt + WUV_OFS;
#pragma unroll
        for (int p = 0; p < 16; ++p) {
            int e = tid + p * 256; int r = e >> 6, c = e & 63;
            Ts[r][c] = f2b(eW1[(size_t)(half * 128 + k0 + r) * 64 + c]);
        }
        __syncthreads();
#pragma unroll
        for (int p = 0; p < 16; ++p) {
            int e = tid + p * 256; int n = e >> 6, k = e & 63;
            Wuv[(size_t)(half * 64 + n) * 128 + k0 + k] = Ts[k][n];
        }
        return;
    }
    if (bid < 253) {
        int e = (bid - 232) * 256 + tid;
        if (e < 5120) {
            int i = e / 10, j = e - i * 10;
            float acc = 0.f;
            for (int h = 0; h < 256; ++h) acc += fW1[(size_t)i * 256 + h] * fW2[(size_t)h * 10 + j];
            Wc[e] = acc;
        } else if (e < 5130) {
            int j = e - 5120;
            float acc = fb2[j];
            for (int h = 0; h < 256; ++h) acc += fb1[h] * fW2[(size_t)h * 10 + j];
            bc[j] = acc;
        }
        return;
    }
    {
        int idx = (bid - 253) * 256 + tid;
        float4 vv = ((const float4*)x)[idx];
        ushort4 o;
        o.x = f2b(vv.x); o.y = f2b(vv.y); o.z = f2b(vv.z); o.w = f2b(vv.w);
        ((ushort4*)xb0)[idx] = o;
    }
}

// ---------------- uv = x @ Wuv (+eb1 on u cols) via bf16 MFMA ----------------
__global__ __launch_bounds__(256) void uv_mfma(const unsigned short* __restrict__ xb0,
                                               const unsigned short* __restrict__ Wuv,
                                               const float* __restrict__ eb1,
                                               float* __restrict__ uv) {
    __shared__ __align__(16) unsigned short As[128 * 40];
    __shared__ __align__(16) unsigned short Bs[64 * 40];
    int tid = threadIdx.x;
    int w = tid >> 6, lane = tid & 63, quad = lane >> 4, lr = lane & 15;
    int row0 = blockIdx.y * 128, col0 = blockIdx.x * 64;
    floatx4 acc[2][4];
#pragma unroll
    for (int rt = 0; rt < 2; ++rt)
#pragma unroll
        for (int ct = 0; ct < 4; ++ct) acc[rt][ct] = (floatx4){0.f, 0.f, 0.f, 0.f};
    int arow[2], asub[2];
#pragma unroll
    for (int i = 0; i < 2; ++i) { int ch = tid + i * 256; arow[i] = ch >> 2; asub[i] = ch & 3; }
    int brow = tid >> 2, bsub = tid & 3;
    for (int k0 = 0; k0 < 128; k0 += 32) {
        short8 ra[2];
#pragma unroll
        for (int i = 0; i < 2; ++i)
            ra[i] = *(const short8*)(xb0 + (size_t)(row0 + arow[i]) * 128 + k0 + asub[i] * 8);
        short8 rb = *(const short8*)(Wuv + (size_t)(col0 + brow) * 128 + k0 + bsub * 8);
        __syncthreads();
#pragma unroll
        for (int i = 0; i < 2; ++i) *(short8*)&As[arow[i] * 40 + asub[i] * 8] = ra[i];
        *(short8*)&Bs[brow * 40 + bsub * 8] = rb;
        __syncthreads();
        short8 a[2], b[4];
#pragma unroll
        for (int rt = 0; rt < 2; ++rt)
            a[rt] = *(const short8*)&As[(w * 32 + rt * 16 + lr) * 40 + quad * 8];
#pragma unroll
        for (int ct = 0; ct < 4; ++ct)
            b[ct] = *(const short8*)&Bs[(ct * 16 + lr) * 40 + quad * 8];
#pragma unroll
        for (int rt = 0; rt < 2; ++rt)
#pragma unroll
            for (int ct = 0; ct < 4; ++ct)
                acc[rt][ct] = __builtin_amdgcn_mfma_f32_16x16x32_bf16(a[rt], b[ct], acc[rt][ct], 0, 0, 0);
    }
#pragma unroll
    for (int rt = 0; rt < 2; ++rt) {
        int rbase = row0 + w * 32 + rt * 16 + quad * 4;
#pragma unroll
        for (int ct = 0; ct < 4; ++ct) {
            int col = col0 + ct * 16 + lr;
            float bi = (col < 64) ? eb1[col] : 0.f;
#pragma unroll
            for (int reg = 0; reg < 4; ++reg)
                uv[(size_t)(rbase + reg) * 128 + col] = acc[rt][ct][reg] + bi;
        }
    }
}

// ---------------- symmetric masked-exp edge scores (upper-tri tile pairs only) ----------------
__global__ __launch_bounds__(256) void edge_sym(const float* __restrict__ uv,
                                                const float* __restrict__ eW2,
                                                const float* __restrict__ eb2,
                                                const float* __restrict__ mask,
                                                float* __restrict__ ap) {
    __shared__ __align__(16) float ui[16][68], vi[16][68], uj[16][68], vj[16][68];
    __shared__ __align__(16) float w2[64];
    int t = blockIdx.x, b = blockIdx.y;
    int ti = 0, rem = t;
    for (;;) { int w = 8 - ti; if (rem < w) break; rem -= w; ++ti; }
    int tj = ti + rem;
    int i0 = ti * 16, j0 = tj * 16;
    int tid = threadIdx.x;
    int r = tid >> 4, c4 = (tid & 15) * 4;
    const float* uvb = uv + (size_t)b * Nn * 128;
    *(float4*)&ui[r][c4] = *(const float4*)(uvb + (size_t)(i0 + r) * 128 + c4);
    *(float4*)&vi[r][c4] = *(const float4*)(uvb + (size_t)(i0 + r) * 128 + 64 + c4);
    *(float4*)&uj[r][c4] = *(const float4*)(uvb + (size_t)(j0 + r) * 128 + c4);
    *(float4*)&vj[r][c4] = *(const float4*)(uvb + (size_t)(j0 + r) * 128 + 64 + c4);
    if (tid < 64) w2[tid] = eW2[tid];
    __syncthreads();
    int il = tid >> 4, jl = tid & 15;
    int gi = i0 + il, gj = j0 + jl;
    if (gj <= gi) return;
    float d = 0.f;
#pragma unroll
    for (int h4 = 0; h4 < 16; ++h4) {
        float4 a1 = *(const float4*)&ui[il][h4 * 4];
        float4 b1 = *(const float4*)&vj[jl][h4 * 4];
        float4 a2 = *(const float4*)&uj[jl][h4 * 4];
        float4 b2 = *(const float4*)&vi[il][h4 * 4];
        float4 ww = *(const float4*)&w2[h4 * 4];
        d += (fmaxf(a1.x + b1.x, 0.f) + fmaxf(a2.x + b2.x, 0.f)) * ww.x
           + (fmaxf(a1.y + b1.y, 0.f) + fmaxf(a2.y + b2.y, 0.f)) * ww.y
           + (fmaxf(a1.z + b1.z, 0.f) + fmaxf(a2.z + b2.z, 0.f)) * ww.z
           + (fmaxf(a1.w + b1.w, 0.f) + fmaxf(a2.w + b2.w, 0.f)) * ww.w;
    }
    float p = 0.5f * d + eb2[0];
    float mi = mask[b * Nn + gi], mj = mask[b * Nn + gj];
    float val = (mi != 0.f && mj != 0.f) ? expf(fminf(p, 80.f)) : 0.f;
    ap[((size_t)(b * Nn + gi)) * Nn + gj] = val;
}

// ---------------- merged: [0,32) An path -> L(rel1); [32,64) A path -> L(rel0) ----------------
__global__ __launch_bounds__(256) void adj_L(const float* __restrict__ ap,
                                             const float* __restrict__ A,
                                             unsigned short* __restrict__ Lb) {
    int bid = blockIdx.x, tid = threadIdx.x;
    if (bid < 32) {
        int b = bid;
        __shared__ float apS[128][129];
        __shared__ float part[256], invS[128], t1S[128], Dv[128];
        const float* apg = ap + (size_t)b * Nn * Nn;
        for (int k = 0; k < 64; ++k) {
            int idx = tid + k * 256;
            int i = idx >> 7, j = idx & 127;
            float g = apg[idx];
            apS[i][j] = (j > i) ? g : 0.f;
        }
        __syncthreads();
        {
            int row = tid >> 1, half = tid & 1;
            float s0 = 0.f;
            for (int j = half * 64; j < half * 64 + 64; ++j) s0 += apS[row][j];
            part[tid] = s0;
        }
        __syncthreads();
        if (tid < 128) {
            float rsum = part[tid * 2] + part[tid * 2 + 1];
            invS[tid] = (rsum == 0.f) ? 1.f : (1.f / rsum);
            t1S[tid]  = (rsum == 0.f) ? 0.f : 1.f;
        }
        __syncthreads();
        {
            int col = tid >> 1, half = tid & 1;
            float s0 = 0.f;
            for (int j = half * 64; j < half * 64 + 64; ++j) s0 += apS[j][col] * invS[j];
            part[tid] = s0;
        }
        __syncthreads();
        if (tid < 128) Dv[tid] = rsqrtf(t1S[tid] + part[tid * 2] + part[tid * 2 + 1] + 1e-5f);
        __syncthreads();
        unsigned short* Lo = Lb + ((size_t)(Bk + b)) * Nn * Nn;
        for (int k = 0; k < 64; ++k) {
            int idx = tid + k * 256;
            int i = idx >> 7, j = idx & 127;
            float an = apS[i][j] * invS[i] + apS[j][i] * invS[j];
            Lo[idx] = f2b(Dv[i] * an * Dv[j]);
        }
    } else {
        int b = bid - 32;
        const float* Ar = A + (size_t)b * Nn * Nn;
        __shared__ float part2[256];
        __shared__ float Ds[128];
        int j = tid & 127, half = tid >> 7;
        float sum = 0.f;
        for (int i = half * 64; i < half * 64 + 64; ++i) sum += Ar[i * Nn + j];
        part2[tid] = sum;
        __syncthreads();
        if (tid < 128) Ds[tid] = rsqrtf(part2[tid] + part2[tid + 128] + 1e-5f);
        __syncthreads();
        unsigned short* Lo = Lb + (size_t)b * Nn * Nn;
        for (int k = 0; k < 64; ++k) {
            int idx = tid + k * 256;
            int i = idx >> 7, jj = idx & 127;
            Lo[idx] = f2b(Ds[i] * Ar[idx] * Ds[jj]);
        }
    }
}

// ---------------- Chebyshev staging v4: L A-frags in registers, T1 then T2, 17 KB LDS ----------------
template <int FIN>
__global__ __launch_bounds__(256) void cheb_v4(const unsigned short* __restrict__ Lb,
                                               const float* __restrict__ xin,
                                               unsigned short* __restrict__ Xb) {
    constexpr int LDK = 136;
    __shared__ __align__(16) unsigned short XsT[32 * LDK];
    __shared__ __align__(16) unsigned short T1T[32 * LDK];
    int z = blockIdx.y;
    int b = z & 31, rel = z >> 5;
    int c0 = blockIdx.x * 32;
    int tid = threadIdx.x;
    int w = tid >> 6, lane = tid & 63, quad = lane >> 4, lr = lane & 15;
    const unsigned short* Lp = Lb + ((size_t)(rel * Bk + b)) * Nn * Nn;
    const float* Xp = xin + (size_t)b * Nn * FIN;
    const int ld6 = 6 * FIN;
    unsigned short* Xo = Xb + (size_t)b * Nn * ld6 + rel * 3 * FIN;

    // ---- preload L A-frags from global (row-private per wave; L2-resident) ----
    short8 aL[2][4];
#pragma unroll
    for (int rt = 0; rt < 2; ++rt) {
        int row = w * 32 + rt * 16 + lr;
#pragma unroll
        for (int kc = 0; kc < 4; ++kc)
            aL[rt][kc] = *(const short8*)(Lp + (size_t)row * Nn + kc * 32 + quad * 8);
    }
    // ---- X col-slice -> XsT (transposed bf16) + T0 writeback ----
    {
        int node = tid >> 1, cb = (tid & 1) * 16;
        const float* xr = Xp + (size_t)node * FIN + c0 + cb;
        unsigned short* t0w = Xo + (size_t)node * ld6 + c0 + cb;
#pragma unroll
        for (int i = 0; i < 4; ++i) {
            float4 vv = *(const float4*)(xr + i * 4);
            ushort4 o;
            o.x = f2b(vv.x); o.y = f2b(vv.y); o.z = f2b(vv.z); o.w = f2b(vv.w);
            *(ushort4*)(t0w + i * 4) = o;
            XsT[(cb + i * 4 + 0) * LDK + node] = o.x;
            XsT[(cb + i * 4 + 1) * LDK + node] = o.y;
            XsT[(cb + i * 4 + 2) * LDK + node] = o.z;
            XsT[(cb + i * 4 + 3) * LDK + node] = o.w;
        }
    }
    __syncthreads();

    // ---- T1 = L @ X ----
    floatx4 acc1[2][2];
#pragma unroll
    for (int rt = 0; rt < 2; ++rt)
#pragma unroll
        for (int ct = 0; ct < 2; ++ct) acc1[rt][ct] = (floatx4){0.f, 0.f, 0.f, 0.f};
#pragma unroll
    for (int kc = 0; kc < 4; ++kc) {
        short8 bb[2];
#pragma unroll
        for (int ct = 0; ct < 2; ++ct)
            bb[ct] = *(const short8*)&XsT[(ct * 16 + lr) * LDK + kc * 32 + quad * 8];
#pragma unroll
        for (int rt = 0; rt < 2; ++rt)
#pragma unroll
            for (int ct = 0; ct < 2; ++ct)
                acc1[rt][ct] = __builtin_amdgcn_mfma_f32_16x16x32_bf16(aL[rt][kc], bb[ct], acc1[rt][ct], 0, 0, 0);
    }
#pragma unroll
    for (int rt = 0; rt < 2; ++rt) {
        int rb = (w * 2 + rt) * 16 + quad * 4;
#pragma unroll
        for (int ct = 0; ct < 2; ++ct) {
            int col = ct * 16 + lr;
            ushort4 o;
            o.x = f2b(acc1[rt][ct][0]); o.y = f2b(acc1[rt][ct][1]);
            o.z = f2b(acc1[rt][ct][2]); o.w = f2b(acc1[rt][ct][3]);
            *(ushort4*)&T1T[col * LDK + rb] = o;
        }
    }
    __syncthreads();

    // ---- T1 writeback + T2 = 2*L@T1 - T0 ----
    {
        int node = tid >> 1, cb = (tid & 1) * 16;
        unsigned short* t1w = Xo + (size_t)node * ld6 + FIN + c0 + cb;
#pragma unroll
        for (int i = 0; i < 4; ++i) {
            ushort4 o;
            o.x = T1T[(cb + i * 4 + 0) * LDK + node];
            o.y = T1T[(cb + i * 4 + 1) * LDK + node];
            o.z = T1T[(cb + i * 4 + 2) * LDK + node];
            o.w = T1T[(cb + i * 4 + 3) * LDK + node];
            *(ushort4*)(t1w + i * 4) = o;
        }
    }
    floatx4 acc2[2][2];
#pragma unroll
    for (int rt = 0; rt < 2; ++rt)
#pragma unroll
        for (int ct = 0; ct < 2; ++ct) acc2[rt][ct] = (floatx4){0.f, 0.f, 0.f, 0.f};
#pragma unroll
    for (int kc = 0; kc < 4; ++kc) {
        short8 bb[2];
#pragma unroll
        for (int ct = 0; ct < 2; ++ct)
            bb[ct] = *(const short8*)&T1T[(ct * 16 + lr) * LDK + kc * 32 + quad * 8];
#pragma unroll
        for (int rt = 0; rt < 2; ++rt)
#pragma unroll
            for (int ct = 0; ct < 2; ++ct)
                acc2[rt][ct] = __builtin_amdgcn_mfma_f32_16x16x32_bf16(aL[rt][kc], bb[ct], acc2[rt][ct], 0, 0, 0);
    }
    // T2 = 2*acc2 - T0 (exact f32 from global); stash T2^T into XsT (safe after barrier 2)
#pragma unroll
    for (int rt = 0; rt < 2; ++rt) {
        int rb = (w * 2 + rt) * 16 + quad * 4;
#pragma unroll
        for (int ct = 0; ct < 2; ++ct) {
            int col = ct * 16 + lr;
            ushort4 o;
            float t0a = Xp[(size_t)(rb + 0) * FIN + c0 + col];
            float t0b = Xp[(size_t)(rb + 1) * FIN + c0 + col];
            float t0c = Xp[(size_t)(rb + 2) * FIN + c0 + col];
            float t0d = Xp[(size_t)(rb + 3) * FIN + c0 + col];
            o.x = f2b(2.f * acc2[rt][ct][0] - t0a);
            o.y = f2b(2.f * acc2[rt][ct][1] - t0b);
            o.z = f2b(2.f * acc2[rt][ct][2] - t0c);
            o.w = f2b(2.f * acc2[rt][ct][3] - t0d);
            *(ushort4*)&XsT[col * LDK + rb] = o;
        }
    }
    __syncthreads();
    {
        int node = tid >> 1, cb = (tid & 1) * 16;
        unsigned short* t2w = Xo + (size_t)node * ld6 + 2 * FIN + c0 + cb;
#pragma unroll
        for (int i = 0; i < 4; ++i) {
            ushort4 o;
            o.x = XsT[(cb + i * 4 + 0) * LDK + node];
            o.y = XsT[(cb + i * 4 + 1) * LDK + node];
            o.z = XsT[(cb + i * 4 + 2) * LDK + node];
            o.w = XsT[(cb + i * 4 + 3) * LDK + node];
            *(ushort4*)(t2w + i * 4) = o;
        }
    }
}

// ---------------- fc via bf16 MFMA + fused bias/mask/BN/relu (+pool+classifier) ----------------
template <int RT, bool POOL>
__global__ __launch_bounds__(256) void fc_mfma(const unsigned short* __restrict__ Xb,
                                               const unsigned short* __restrict__ Wt,
                                               const float* __restrict__ bias,
                                               const float* __restrict__ mask,
                                               const float* __restrict__ bnG,
                                               const float* __restrict__ bnB,
                                               const float* __restrict__ bnM,
                                               const float* __restrict__ bnV,
                                               float* __restrict__ out,
                                               const float* __restrict__ Wc,
                                               const float* __restrict__ bc,
                                               float* __restrict__ outc,
                                               int Kd, int F) {
    __shared__ __align__(16) unsigned short As[RT * 64 * 40];
    __shared__ __align__(16) unsigned short Bs[64 * 40];
    __shared__ float wmax[4][64];
    int tid = threadIdx.x;
    int w = tid >> 6, lane = tid & 63, quad = lane >> 4, lr = lane & 15;
    int row0 = blockIdx.y * (RT * 64), col0 = blockIdx.x * 64;

    floatx4 acc[RT][4];
#pragma unroll
    for (int rt = 0; rt < RT; ++rt)
#pragma unroll
        for (int ct = 0; ct < 4; ++ct) acc[rt][ct] = (floatx4){0.f, 0.f, 0.f, 0.f};

    int arow[RT], asub[RT];
#pragma unroll
    for (int i = 0; i < RT; ++i) { int ch = tid + i * 256; arow[i] = ch >> 2; asub[i] = ch & 3; }
    int brow = tid >> 2, bsub = tid & 3;

    for (int k0 = 0; k0 < Kd; k0 += 32) {
        short8 ra[RT];
#pragma unroll
        for (int i = 0; i < RT; ++i)
            ra[i] = *(const short8*)(Xb + (size_t)(row0 + arow[i]) * Kd + k0 + asub[i] * 8);
        short8 rb = *(const short8*)(Wt + (size_t)(col0 + brow) * Kd + k0 + bsub * 8);
        __syncthreads();
#pragma unroll
        for (int i = 0; i < RT; ++i)
            *(short8*)&As[arow[i] * 40 + asub[i] * 8] = ra[i];
        *(short8*)&Bs[brow * 40 + bsub * 8] = rb;
        __syncthreads();
        short8 a[RT], b[4];
#pragma unroll
        for (int rt = 0; rt < RT; ++rt)
            a[rt] = *(const short8*)&As[(w * RT * 16 + rt * 16 + lr) * 40 + quad * 8];
#pragma unroll
        for (int ct = 0; ct < 4; ++ct)
            b[ct] = *(const short8*)&Bs[(ct * 16 + lr) * 40 + quad * 8];
#pragma unroll
        for (int rt = 0; rt < RT; ++rt)
#pragma unroll
            for (int ct = 0; ct < 4; ++ct)
                acc[rt][ct] = __builtin_amdgcn_mfma_f32_16x16x32_bf16(a[rt], b[ct], acc[rt][ct], 0, 0, 0);
    }

    float cm[4] = {0.f, 0.f, 0.f, 0.f};
#pragma unroll
    for (int rt = 0; rt < RT; ++rt) {
        int rbase = row0 + w * RT * 16 + rt * 16 + quad * 4;
#pragma unroll
        for (int ct = 0; ct < 4; ++ct) {
            int col = col0 + ct * 16 + lr;
            float bi = bias[col];
            float sc = rsqrtf(bnV[col] + BN_EPS) * bnG[col];
            float bm = bnM[col], bb = bnB[col];
#pragma unroll
            for (int reg = 0; reg < 4; ++reg) {
                int row = rbase + reg;
                float h = acc[rt][ct][reg] + bi;
                h *= mask[row];
                h = (h - bm) * sc + bb;
                h = fmaxf(h, 0.f);
                if (POOL) cm[ct] = fmaxf(cm[ct], h);
                else      out[(size_t)row * F + col] = h;
            }
        }
    }
    if (POOL) {
#pragma unroll
        for (int ct = 0; ct < 4; ++ct) {
            cm[ct] = fmaxf(cm[ct], __shfl_xor(cm[ct], 16));
            cm[ct] = fmaxf(cm[ct], __shfl_xor(cm[ct], 32));
            if (quad == 0) wmax[w][ct * 16 + lr] = cm[ct];
        }
        __syncthreads();
        if (tid < 64) {
            float g = fmaxf(fmaxf(wmax[0][tid], wmax[1][tid]), fmaxf(wmax[2][tid], wmax[3][tid]));
            // fold classifier: partial[o] = sum over this block's 64 cols of g * Wc[col][o]
            float s[10];
#pragma unroll
            for (int o = 0; o < 10; ++o) s[o] = g * Wc[(size_t)(col0 + tid) * 10 + o];
#pragma unroll
            for (int ofs = 32; ofs > 0; ofs >>= 1)
#pragma unroll
                for (int o = 0; o < 10; ++o) s[o] += __shfl_down(s[o], ofs);
            if (tid == 0) {
                int b = blockIdx.y;
#pragma unroll
                for (int o = 0; o < 10; ++o) {
                    float v = s[o] + ((blockIdx.x == 0) ? bc[o] : 0.f);
                    atomicAdd(&outc[b * 10 + o], v);
                }
            }
        }
    }
}

extern "C" void kernel_launch(void* const* d_in, const int* in_sizes, int n_in,
                              void* d_out, int out_size, void* d_ws, size_t ws_size,
                              hipStream_t stream) {
    const float* x    = (const float*)d_in[0];
    const float* Ain  = (const float*)d_in[1];
    const float* mask = (const float*)d_in[2];
    const float* eW1  = (const float*)d_in[3];
    const float* eb1  = (const float*)d_in[4];
    const float* eW2  = (const float*)d_in[5];
    const float* eb2  = (const float*)d_in[6];
    const float* fW1  = (const float*)d_in[25];
    const float* fb1  = (const float*)d_in[26];
    const float* fW2  = (const float*)d_in[27];
    const float* fb2  = (const float*)d_in[28];

    float* ws = (float*)d_ws;
    float* uv = ws + OFF_UV;
    float* ap = ws + OFF_AP;
    unsigned short* Lb = (unsigned short*)(ws + OFF_LB);
    float* h0 = ws + OFF_H0;
    float* h1 = ws + OFF_H1;
    float* Wc = ws + OFF_WC;
    float* bc = ws + OFF_BC;
    unsigned short* xb0 = (unsigned short*)(ws + OFF_XB0);
    unsigned short* Xb  = (unsigned short*)(ws + OFF_XB);
    unsigned short* Wt  = (unsigned short*)(ws + OFF_WT);

    // zero the (atomic-accumulated) output
    hipMemsetAsync(d_out, 0, (size_t)out_size * sizeof(float), stream);

    prep_all<<<765, 256, 0, stream>>>((const float*)d_in[7], (const float*)d_in[13],
                                      (const float*)d_in[19], eW1, fW1, fb1, fW2, fb2, x,
                                      Wt, Wc, bc, xb0);

    uv_mfma<<<dim3(2, 32), 256, 0, stream>>>(xb0, Wt + WUV_OFS, eb1, uv);
    edge_sym<<<dim3(36, Bk), 256, 0, stream>>>(uv, eW2, eb2, mask, ap);
    adj_L<<<64, 256, 0, stream>>>(ap, Ain, Lb);

    const float* xins[3] = {x, h0, h1};
    const unsigned short* Wts[3] = {Wt, Wt + 49152, Wt + 147456};
    const int Kds[3] = {768, 384, 1536};
    for (int li = 0; li < 3; ++li) {
        int base = 7 + li * 6;
        const float* gb = (const float*)d_in[base + 1];
        const float* gg = (const float*)d_in[base + 2];
        const float* gB = (const float*)d_in[base + 3];
        const float* gm = (const float*)d_in[base + 4];
        const float* gv = (const float*)d_in[base + 5];

        if (li == 0)      cheb_v4<128><<<dim3(4, 64), 256, 0, stream>>>(Lb, xins[li], Xb);
        else if (li == 1) cheb_v4<64><<<dim3(2, 64), 256, 0, stream>>>(Lb, xins[li], Xb);
        else              cheb_v4<256><<<dim3(8, 64), 256, 0, stream>>>(Lb, xins[li], Xb);

        if (li == 0)
            fc_mfma<1, false><<<dim3(1, 64), 256, 0, stream>>>(
                Xb, Wts[li], gb, mask, gg, gB, gm, gv, h0, nullptr, nullptr, nullptr, Kds[li], 64);
        else if (li == 1)
            fc_mfma<2, false><<<dim3(4, 32), 256, 0, stream>>>(
                Xb, Wts[li], gb, mask, gg, gB, gm, gv, h1, nullptr, nullptr, nullptr, Kds[li], 256);
        else
            fc_mfma<2, true><<<dim3(8, 32), 256, 0, stream>>>(
                Xb, Wts[li], gb, mask, gg, gB, gm, gv, nullptr, Wc, bc, (float*)d_out, Kds[li], 512);
    }
}